// Round 15
// baseline (2947.950 us; speedup 1.0000x reference)
//
#include <hip/hip_runtime.h>

typedef unsigned int u32;

#define NIN 7
#define NB 256
#define NS 2048

__device__ __forceinline__ float fastrcp(float x){ return __builtin_amdgcn_rcpf(x); }
__device__ __forceinline__ float sigf(float x){ return fastrcp(1.f + __expf(-x)); }
__device__ __forceinline__ float tanhf_(float x){ return 1.f - 2.f*fastrcp(1.f + __expf(2.f*x)); }

// RNE f16 pack (activations stay f32 everywhere)
__device__ __forceinline__ u32 pkh(float a, float b){
  unsigned short ua = __builtin_bit_cast(unsigned short, (_Float16)a);
  unsigned short ub = __builtin_bit_cast(unsigned short, (_Float16)b);
  return (u32)ua | ((u32)ub << 16);
}

template<int J>
__device__ __forceinline__ float rlf(float v){
  return __uint_as_float((unsigned)__builtin_amdgcn_readlane((int)__float_as_uint(v), J));
}
__device__ __forceinline__ float rlfv(float v, int j){
  return __uint_as_float((unsigned)__builtin_amdgcn_readlane((int)__float_as_uint(v), j));
}

// acc += f16(lo/hi of wp) * act(f32) + acc, f32 accumulate.
__device__ __forceinline__ float mxl(float acc, u32 wp, float a){
  asm("v_fma_mix_f32 %0, %1, %2, %3 op_sel_hi:[1,0,0]"
      : "=v"(acc) : "v"(wp), "s"(a), "0"(acc));
  return acc;
}
__device__ __forceinline__ float mxh(float acc, u32 wp, float a){
  asm("v_fma_mix_f32 %0, %1, %2, %3 op_sel:[1,0,0] op_sel_hi:[1,0,0]"
      : "=v"(acc) : "v"(wp), "s"(a), "0"(acc));
  return acc;
}
__device__ __forceinline__ float mxlv(float acc, u32 wp, float a){
  asm("v_fma_mix_f32 %0, %1, %2, %3 op_sel_hi:[1,0,0]"
      : "=v"(acc) : "v"(wp), "v"(a), "0"(acc));
  return acc;
}
__device__ __forceinline__ float mxhv(float acc, u32 wp, float a){
  asm("v_fma_mix_f32 %0, %1, %2, %3 op_sel:[1,0,0] op_sel_hi:[1,0,0]"
      : "=v"(acc) : "v"(wp), "v"(a), "0"(acc));
  return acc;
}

__device__ __forceinline__ float gate4(float zi, float zf, float zg, float zo, float& c){
  c = sigf(zf)*c + sigf(zi)*tanhf_(zg);
  return sigf(zo)*tanhf_(c);
}

// 8-elem x+bias dot: w[KB..KB+3] . {v0,v1}
#define XD(a0, a1, KB, v0, v1) { \
  a0 = mxlv(a0, w[(KB)+0], (v0).x); a1 = mxhv(a1, w[(KB)+0], (v0).y); \
  a0 = mxlv(a0, w[(KB)+1], (v0).z); a1 = mxhv(a1, w[(KB)+1], (v0).w); \
  a0 = mxlv(a0, w[(KB)+2], (v1).x); a1 = mxhv(a1, w[(KB)+2], (v1).y); \
  a0 = mxlv(a0, w[(KB)+3], (v1).z); a1 = mxhv(a1, w[(KB)+3], (v1).w); }

// ---- LDS-broadcast dots (uniform float4 reads) ----
#define LMX1(a0, a1, KA, H4) { _Pragma("unroll") \
  for (int c_ = 0; c_ < 16; c_++){ \
    float4 h_ = (H4)[c_]; \
    a0 = mxlv(a0, w[(KA)+2*c_],   h_.x); a1 = mxhv(a1, w[(KA)+2*c_],   h_.y); \
    a0 = mxlv(a0, w[(KA)+2*c_+1], h_.z); a1 = mxhv(a1, w[(KA)+2*c_+1], h_.w); } }

#define LMXH(z0, z1, KB, H4) { _Pragma("unroll") \
  for (int c_ = 0; c_ < 8; c_++){ \
    float4 h_ = (H4)[c_]; \
    z0 = mxlv(z0, w[(KB)+2*c_],   h_.x); z1 = mxhv(z1, w[(KB)+2*c_],   h_.y); \
    z0 = mxlv(z0, w[(KB)+2*c_+1], h_.z); z1 = mxhv(z1, w[(KB)+2*c_+1], h_.w); } }

// ---- readlane dots (prologue only) ----
#define MX1(a0, a1, KA, SRC) { _Pragma("unroll") \
  for (int k_ = 0; k_ < 32; k_++){ \
    float e0_ = rlfv(SRC, 2*k_), e1_ = rlfv(SRC, 2*k_+1); \
    a0 = mxl(a0, w[(KA)+k_], e0_); a1 = mxh(a1, w[(KA)+k_], e1_); } }

#define MXH16(z0, z1, KB, SRC) { _Pragma("unroll") \
  for (int k_ = 0; k_ < 16; k_++){ \
    float e0_ = rlfv(SRC, 2*k_), e1_ = rlfv(SRC, 2*k_+1); \
    z0 = mxl(z0, w[(KB)+k_], e0_); z1 = mxh(z1, w[(KB)+k_], e1_); } }

#define MXH16HI(z0, z1, KB, SRC) { _Pragma("unroll") \
  for (int k_ = 0; k_ < 16; k_++){ \
    float e0_ = rlfv(SRC, 32+2*k_), e1_ = rlfv(SRC, 33+2*k_); \
    z0 = mxl(z0, w[(KB)+k_], e0_); z1 = mxh(z1, w[(KB)+k_], e1_); } }

// MLP with 4 accumulator chains per layer
#define MLPX(HS_, M1B, B1V, M2B, B2V, dres) { \
  float q0_ = (B1V), q1_ = 0.f, q2_ = 0.f, q3_ = 0.f; \
  _Pragma("unroll") \
  for (int j_ = 0; j_ < 16; j_++){ \
    float e0_ = rlfv(HS_, 2*j_), e1_ = rlfv(HS_, 2*j_+1); \
    if ((j_&1)==0){ q0_ = mxl(q0_, w[(M1B)+j_], e0_); q1_ = mxh(q1_, w[(M1B)+j_], e1_); } \
    else          { q2_ = mxl(q2_, w[(M1B)+j_], e0_); q3_ = mxh(q3_, w[(M1B)+j_], e1_); } } \
  float qq_ = fmaxf((q0_+q2_) + (q1_+q3_), 0.f); \
  float f0_ = (B2V), f1_ = 0.f, f2_ = 0.f, f3_ = 0.f; \
  _Pragma("unroll") \
  for (int j_ = 0; j_ < 8; j_++){ \
    float e0_ = rlfv(qq_, 2*j_), e1_ = rlfv(qq_, 2*j_+1); \
    if ((j_&1)==0){ f0_ = mxl(f0_, w[(M2B)+j_], e0_); f1_ = mxh(f1_, w[(M2B)+j_], e1_); } \
    else          { f2_ = mxl(f2_, w[(M2B)+j_], e0_); f3_ = mxh(f3_, w[(M2B)+j_], e1_); } } \
  dres = (f0_+f2_) + (f1_+f3_); }

__global__ __launch_bounds__(512, 1) void mtinn_kernel(
    const float* __restrict__ x,
    const float* wihs, const float* whhs, const float* bihs, const float* bhhs,
    const float* wiha, const float* whha, const float* biha, const float* bhha,
    const float* wihv, const float* whhv, const float* bihv, const float* bhhv,
    const float* wihp, const float* whhp, const float* bihp, const float* bhhp,
    const float* wa1, const float* ba1, const float* wa2, const float* ba2,
    const float* wv1, const float* bv1, const float* wv2, const float* bv2,
    const float* wp1, const float* bp1, const float* wp2, const float* bp2,
    float* __restrict__ out)
{
  __shared__ __align__(16) float ZSL[2][192];  // shared z lo-half partials (i,f,g quarters)
  __shared__ __align__(16) float ZSH[2][192];  // hi-half partials (incl x+bias)
  __shared__ __align__(16) float ZSO[2][64];   // o-quarter (full, from w4)
  __shared__ __align__(16) float ZC[3][128];   // cell z (TOP->TAIL)
  __shared__ __align__(16) float HS[64];       // hs(t+1), from w4
  __shared__ __align__(16) float HA[32], HV[32];
  __shared__ __align__(16) float HPb[2][32];
  __shared__ __align__(16) float XL[4][8];     // x ring; slot[7]=1.0

  const int tid  = threadIdx.x;
  const int wave = tid >> 6, lane = tid & 63, l = lane & 31;
  const int b    = blockIdx.x;
  const float* xb = x + (size_t)b * NS * NIN;

  // roles (SIMD = wave&3):
  //   wave | phase A                          | phase B
  //   w0   | x-prefetch                       | TAIL
  //   w4   | T_hs gate + deferred POS MLP     | sh o-row dot -> ZSO
  //   w1   | TOP att1                         | WIN att1 + sh i_lo
  //   w5   | TOP vel0                         | WIN vel0 + sh i_hi+x
  //   w2   | TOP vel1                         | WIN vel1 + sh f_lo
  //   w6   | TOP pos0                         | WIN pos0 + sh f_hi+x
  //   w3   | TOP pos1                         | WIN pos1 + sh g_lo
  //   w7   | TOP att0                         | WIN att0 + sh g_hi+x
  const bool isWin = (wave != 0 && wave != 4);
  const int  wc    = (wave==1||wave==7) ? 0 : (wave==2||wave==5) ? 1 : 2;
  const int  wrb   = (wave <= 3) ? 64 : 0;
  const bool shHi  = (wave >= 5);                           // w5,w6,w7
  const int  qoff  = (wave==1||wave==5) ? 0 : (wave==2||wave==6) ? 64 : 128;
  const int  mi = lane & 15, mm = lane % 3;

  // ---- packed f16 register weights, union size 72 ----
  // WIN: [0..15] hh | [16..47] hs | [48..51] x+bias | [52..67] sh-hs-half | [68..71] sh x+bias (hi only)
  // w0:  [0..15] m1a | [16..31] m1v | [32..39] m2a | [40..47] m2v | [48..55] velD | [56..63] posD
  // w4:  [0..15] m1p | [16..23] m2p | [24..55] sh-o hs | [56..59] sh-o x+bias
  u32 w[72];
#pragma unroll
  for (int i = 0; i < 72; i++) w[i] = 0u;
  float b1a=0.f,b2a=0.f,b1v=0.f,b2v=0.f,b1p=0.f,b2p=0.f;

  if (isWin){
    const float* wih = (wc==0) ? wiha : (wc==1) ? wihv : wihp;
    const float* whh = (wc==0) ? whha : (wc==1) ? whhv : whhp;
    const float* bi  = (wc==0) ? biha : (wc==1) ? bihv : bihp;
    const float* bh  = (wc==0) ? bhha : (wc==1) ? bhhv : bhhp;
    const int L = (wc==0) ? 71 : (wc==1) ? 74 : 67;
    const int r = wrb + lane;
#pragma unroll
    for (int k=0;k<16;k++) w[k] = pkh(whh[r*32+2*k], whh[r*32+2*k+1]);
#pragma unroll
    for (int k=0;k<32;k++) w[16+k] = pkh(wih[r*L+2*k], wih[r*L+2*k+1]);
    const float bsum = bi[r] + bh[r];
    if (wc==0){
      w[48]=pkh(wih[r*L+64],wih[r*L+65]); w[49]=pkh(wih[r*L+66],wih[r*L+67]);
      w[50]=pkh(wih[r*L+68],wih[r*L+69]); w[51]=pkh(wih[r*L+70], bsum);
    } else if (wc==1){
      w[48]=pkh(wih[r*L+67],wih[r*L+68]); w[49]=pkh(wih[r*L+69],wih[r*L+70]);
      w[50]=pkh(wih[r*L+71],wih[r*L+72]); w[51]=pkh(wih[r*L+73], bsum);
    } else {
      w[51]=pkh(0.f, bsum);
    }
    const int rs = qoff + lane;                          // shared row (i/f/g quarter)
    if (!shHi){
#pragma unroll
      for (int k=0;k<16;k++) w[52+k] = pkh(whhs[rs*64+2*k], whhs[rs*64+2*k+1]);
    } else {
#pragma unroll
      for (int k=0;k<16;k++) w[52+k] = pkh(whhs[rs*64+32+2*k], whhs[rs*64+33+2*k]);
      w[68]=pkh(wihs[rs*7+0],wihs[rs*7+1]); w[69]=pkh(wihs[rs*7+2],wihs[rs*7+3]);
      w[70]=pkh(wihs[rs*7+4],wihs[rs*7+5]); w[71]=pkh(wihs[rs*7+6], bihs[rs]+bhhs[rs]);
    }
  }
  if (wave == 0){
#pragma unroll
    for (int k=0;k<16;k++){
      w[k]    = pkh(wa1[mi*32+2*k], wa1[mi*32+2*k+1]);
      w[16+k] = pkh(wv1[mi*32+2*k], wv1[mi*32+2*k+1]);
    }
#pragma unroll
    for (int k=0;k<8;k++){
      w[32+k] = pkh(wa2[mm*16+2*k], wa2[mm*16+2*k+1]);
      w[40+k] = pkh(wv2[mm*16+2*k], wv2[mm*16+2*k+1]);
    }
#pragma unroll
    for (int g=0; g<4; g++){
      int rr = g*32 + l;
      w[48+2*g]   = pkh(wihv[rr*74+64], wihv[rr*74+65]);
      w[48+2*g+1] = pkh(wihv[rr*74+66], 0.f);
      w[56+2*g]   = pkh(wihp[rr*67+64], wihp[rr*67+65]);
      w[56+2*g+1] = pkh(wihp[rr*67+66], 0.f);
    }
    b1a=ba1[mi]; b2a=ba2[mm]; b1v=bv1[mi]; b2v=bv2[mm];
  }
  if (wave == 4){
#pragma unroll
    for (int k=0;k<16;k++) w[k] = pkh(wp1[mi*32+2*k], wp1[mi*32+2*k+1]);
#pragma unroll
    for (int k=0;k<8;k++)  w[16+k] = pkh(wp2[mm*16+2*k], wp2[mm*16+2*k+1]);
    const int ro = 192 + lane;                           // o-quarter row
#pragma unroll
    for (int k=0;k<32;k++) w[24+k] = pkh(whhs[ro*64+2*k], whhs[ro*64+2*k+1]);
    w[56]=pkh(wihs[ro*7+0],wihs[ro*7+1]); w[57]=pkh(wihs[ro*7+2],wihs[ro*7+3]);
    w[58]=pkh(wihs[ro*7+4],wihs[ro*7+5]); w[59]=pkh(wihs[ro*7+6], bihs[ro]+bhhs[ro]);
    b1p=bp1[mi]; b2p=bp2[mm];
  }

  // ---- LDS init ----
  if (tid < 32) HA[tid]=0.f;
  else if (tid < 64)  HV[tid-32]=0.f;
  else if (tid < 96)  HPb[0][tid-64]=0.f;
  else if (tid < 128) HPb[1][tid-96]=0.f;
  if (tid < 8){
    XL[0][tid] = (tid<7) ? xb[tid]         : 1.f;
    XL[1][tid] = (tid<7) ? xb[NIN+tid]     : 1.f;
    XL[2][tid] = (tid<7) ? xb[2*NIN+tid]   : 1.f;
    XL[3][tid] = 1.f;
  }
  __syncthreads();

  // ---- prologue 1: zS(0) = b + Wih x(0)  (x-parts only; h=0) ----
  {
    const float4* X0 = (const float4*)XL[0];
    float4 xa = X0[0], xb4 = X0[1];
    if (isWin && !shHi) ZSL[0][qoff + lane] = 0.f;
    if (isWin && shHi){
      float s0=0.f, s1=0.f; XD(s0,s1,68,xa,xb4);
      ZSH[0][qoff + lane] = s0 + s1;
      ZSL[1][qoff + lane] = 0.f;                        // scratch init (overwritten below by lo waves)
    }
    if (wave == 4){
      float o0=0.f, o1=0.f; XD(o0,o1,56,xa,xb4);
      ZSO[0][lane] = o0 + o1;
    }
  }
  __syncthreads();

  float c_s = 0.f;                          // w4
  float c_a = 0.f, c_v = 0.f, c_p = 0.f;    // w0
  float zpart = 0.f;

  // ---- prologue 2: hs(0), zpart(0), zS(1) partials ----
  {
    const float4* X0 = (const float4*)XL[0];
    const float4* X1 = (const float4*)XL[1];
    if (isWin){
      float zi_=ZSL[0][lane]+ZSH[0][lane], zf_=ZSL[0][64+lane]+ZSH[0][64+lane];
      float zg_=ZSL[0][128+lane]+ZSH[0][128+lane], zo_=ZSO[0][lane];
      float cd = 0.f;
      float hsv = gate4(zi_,zf_,zg_,zo_, cd);
      float4 xa = X0[0], xb4 = X0[1];
      float a0=0.f, a1=0.f; XD(a0,a1,48,xa,xb4);
      MX1(a0,a1,16,hsv);
      zpart = a0 + a1;
      float s0=0.f, s1=0.f;
      if (!shHi){
        MXH16(s0,s1,52,hsv);
        ZSL[1][qoff + lane] = s0 + s1;
      } else {
        MXH16HI(s0,s1,52,hsv);
        float4 xc = X1[0], xd = X1[1];
        XD(s0,s1,68,xc,xd);
        ZSH[1][qoff + lane] = s0 + s1;
      }
    } else if (wave == 4){
      float zi_=ZSL[0][lane]+ZSH[0][lane], zf_=ZSL[0][64+lane]+ZSH[0][64+lane];
      float zg_=ZSL[0][128+lane]+ZSH[0][128+lane], zo_=ZSO[0][lane];
      float hsv = gate4(zi_,zf_,zg_,zo_, c_s);           // warm c_s(0)
      float o0=0.f, o1=0.f;
      MX1(o0,o1,24,hsv);
      float4 xc = X1[0], xd = X1[1];
      XD(o0,o1,56,xc,xd);
      ZSO[1][lane] = o0 + o1;
    }
  }
  __syncthreads();

  // ================= pipelined recurrence =================
#pragma unroll 1
  for (int t = 0; t < NS; t++){
    float xpre = 0.f;
    // ---- PHASE A ----
    if (wave == 0){
      if (lane < 7){
        const int tf = (t+3 < NS) ? t+3 : NS-1;
        xpre = xb[(size_t)tf*NIN + lane];
      }
    } else if (wave == 4){
      const int rb = (t+1)&1;
      float zi_=ZSL[rb][lane]+ZSH[rb][lane], zf_=ZSL[rb][64+lane]+ZSH[rb][64+lane];
      float zg_=ZSL[rb][128+lane]+ZSH[rb][128+lane], zo_=ZSO[rb][lane];
      float hsv2 = gate4(zi_,zf_,zg_,zo_, c_s);
      HS[lane] = hsv2;
      if (t > 0){
        float hp_ = HPb[(t^1)&1][l];
        float dP; MLPX(hp_, 0, b1p, 16, b2p, dP);
        if (lane < 3) out[((size_t)b*NS + (t-1))*9 + 6 + lane] = dP;
      }
    } else {
      const float4* H4 = (const float4*)((wc==0) ? HA : (wc==1) ? HV : HPb[(t^1)&1]);
      float z0 = zpart, z1 = 0.f;
      LMXH(z0,z1,0,H4);
      ZC[wc][wrb + lane] = z0 + z1;
    }
    __syncthreads();   // #1 : ZC(t), HS(t+1) visible

    // ---- PHASE B ----
    if (wave == 0){
      // ================= TAIL =================
      float zai=ZC[0][l], zaf=ZC[0][32+l], zag=ZC[0][64+l], zao=ZC[0][96+l];
      float zvi=ZC[1][l], zvf=ZC[1][32+l], zvg=ZC[1][64+l], zvo=ZC[1][96+l];
      float zpi=ZC[2][l], zpf=ZC[2][32+l], zpg=ZC[2][64+l], zpo=ZC[2][96+l];
      float* ob = out + ((size_t)b*NS + t)*9;
      // ATT
      float ha = gate4(zai,zaf,zag,zao, c_a);
      if (lane < 32) HA[lane] = ha;
      float dA; MLPX(ha, 0, b1a, 32, b2a, dA);
      if (lane < 3) ob[lane] = dA;
      float dx=rlf<0>(dA), dy=rlf<1>(dA), dz=rlf<2>(dA);
      // VEL (+ d_att columns)
      zvi = mxl(zvi, w[48], dx); zvi = mxh(zvi, w[48], dy); zvi = mxl(zvi, w[49], dz);
      zvf = mxl(zvf, w[50], dx); zvf = mxh(zvf, w[50], dy); zvf = mxl(zvf, w[51], dz);
      zvg = mxl(zvg, w[52], dx); zvg = mxh(zvg, w[52], dy); zvg = mxl(zvg, w[53], dz);
      zvo = mxl(zvo, w[54], dx); zvo = mxh(zvo, w[54], dy); zvo = mxl(zvo, w[55], dz);
      float hv = gate4(zvi,zvf,zvg,zvo, c_v);
      if (lane < 32) HV[lane] = hv;
      float dV; MLPX(hv, 16, b1v, 40, b2v, dV);
      if (lane < 3) ob[3+lane] = dV;
      dx=rlf<0>(dV); dy=rlf<1>(dV); dz=rlf<2>(dV);
      // POS (+ d_vel columns); MLP deferred to w4
      zpi = mxl(zpi, w[56], dx); zpi = mxh(zpi, w[56], dy); zpi = mxl(zpi, w[57], dz);
      zpf = mxl(zpf, w[58], dx); zpf = mxh(zpf, w[58], dy); zpf = mxl(zpf, w[59], dz);
      zpg = mxl(zpg, w[60], dx); zpg = mxh(zpg, w[60], dy); zpg = mxl(zpg, w[61], dz);
      zpo = mxl(zpo, w[62], dx); zpo = mxh(zpo, w[62], dy); zpo = mxl(zpo, w[63], dz);
      float hp_ = gate4(zpi,zpf,zpg,zpo, c_p);
      if (lane < 32) HPb[t&1][lane] = hp_;
      if (lane < 7) XL[(t+3)&3][lane] = xpre;
    } else if (wave == 4){
      // sh o-row: zS_o(t+2) = Wo_hs . hs(t+1) + Wo_x . x(t+2) + b
      const float4* H4 = (const float4*)HS;
      float o0=0.f, o1=0.f;
      LMX1(o0,o1,24,H4);
      const float4* X2 = (const float4*)XL[(t+2)&3];
      float4 xc = X2[0], xd = X2[1];
      XD(o0,o1,56,xc,xd);
      ZSO[t&1][lane] = o0 + o1;
    } else {
      // WIN: zpart(t+1) + sh half of zS(t+2)
      const float4* H4 = (const float4*)HS;
      const float4* X1 = (const float4*)XL[(t+1)&3];
      float4 xa = X1[0], xb4 = X1[1];
      float a0=0.f, a1=0.f; XD(a0,a1,48,xa,xb4);
      LMX1(a0,a1,16,H4);
      zpart = a0 + a1;
      float s0=0.f, s1=0.f;
      if (!shHi){
        LMXH(s0,s1,52,H4);
        ZSL[t&1][qoff + lane] = s0 + s1;
      } else {
        LMXH(s0,s1,52,H4+8);
        const float4* X2 = (const float4*)XL[(t+2)&3];
        float4 xc = X2[0], xd = X2[1];
        XD(s0,s1,68,xc,xd);
        ZSH[t&1][qoff + lane] = s0 + s1;
      }
    }
    __syncthreads();   // #2
  }

  // ---- epilogue: POS MLP for t = NS-1 ----
  if (wave == 4){
    float hp_ = HPb[(NS-1)&1][l];
    float dP; MLPX(hp_, 0, b1p, 16, b2p, dP);
    if (lane < 3) out[((size_t)b*NS + (NS-1))*9 + 6 + lane] = dP;
  }
}

extern "C" void kernel_launch(void* const* d_in, const int* in_sizes, int n_in,
                              void* d_out, int out_size, void* d_ws, size_t ws_size,
                              hipStream_t stream) {
  (void)in_sizes; (void)n_in; (void)d_ws; (void)ws_size; (void)out_size;
  const float* X    = (const float*)d_in[0];
  const float* Wihs = (const float*)d_in[1];
  const float* Whhs = (const float*)d_in[2];
  const float* Bihs = (const float*)d_in[3];
  const float* Bhhs = (const float*)d_in[4];
  const float* Wiha = (const float*)d_in[5];
  const float* Whha = (const float*)d_in[6];
  const float* Biha = (const float*)d_in[7];
  const float* Bhha = (const float*)d_in[8];
  const float* Wihv = (const float*)d_in[9];
  const float* Whhv = (const float*)d_in[10];
  const float* Bihv = (const float*)d_in[11];
  const float* Bhhv = (const float*)d_in[12];
  const float* Wihp = (const float*)d_in[13];
  const float* Whhp = (const float*)d_in[14];
  const float* Bihp = (const float*)d_in[15];
  const float* Bhhp = (const float*)d_in[16];
  const float* Wa1  = (const float*)d_in[17];
  const float* Ba1  = (const float*)d_in[18];
  const float* Wa2  = (const float*)d_in[19];
  const float* Ba2  = (const float*)d_in[20];
  const float* Wv1  = (const float*)d_in[21];
  const float* Bv1  = (const float*)d_in[22];
  const float* Wv2  = (const float*)d_in[23];
  const float* Bv2  = (const float*)d_in[24];
  const float* Wp1  = (const float*)d_in[25];
  const float* Bp1  = (const float*)d_in[26];
  const float* Wp2  = (const float*)d_in[27];
  const float* Bp2  = (const float*)d_in[28];
  float* OUTP = (float*)d_out;

  mtinn_kernel<<<dim3(NB), dim3(512), 0, stream>>>(
      X, Wihs, Whhs, Bihs, Bhhs,
      Wiha, Whha, Biha, Bhha,
      Wihv, Whhv, Bihv, Bhhv,
      Wihp, Whhp, Bihp, Bhhp,
      Wa1, Ba1, Wa2, Ba2, Wv1, Bv1, Wv2, Bv2, Wp1, Bp1, Wp2, Bp2,
      OUTP);
}